// Round 5
// baseline (675.597 us; speedup 1.0000x reference)
//
#include <hip/hip_runtime.h>
#include <math.h>

#define BB 8
#define LAT 128
#define HH 1024
#define KK 294
#define NN 100000
#define EE 1600000
#define NSTEPS 3
#define XS_HALF 64.0f

#define NB 391      // ceil(NN/256)
#define FS 4        // flow_init k-splits
#define FCH 74      // ceil(294/4)
#define CS 8        // coef j-splits (128 each)
#define COB 28      // ceil(7056/256)
#define ONODES 512  // k_out nodes per block

// ---------------- decode MLP: split-K GEMM ----------------
__global__ void k_mlp_part(const float* __restrict__ hin, const float* __restrict__ W,
                           float* __restrict__ part, int jdim) {
    int it = blockIdx.x & 15;
    int bs = blockIdx.x >> 4;
    int tx = threadIdx.x;
    int il = tx & 63;
    int jg = tx >> 6;          // wave id 0..3
    int i = it * 64 + il;
    int j0 = bs * 64;

    __shared__ float hs[8 * 64];
    for (int u = tx; u < 512; u += 256) {
        int b = u >> 6, lj = u & 63;
        hs[u] = hin[b * jdim + j0 + lj];
    }
    __syncthreads();

    float acc[8];
#pragma unroll
    for (int b = 0; b < 8; ++b) acc[b] = 0.0f;
#pragma unroll
    for (int jj = 0; jj < 16; ++jj) {
        int lj = jg * 16 + jj;
        float w = W[(size_t)(j0 + lj) * HH + i];
#pragma unroll
        for (int b = 0; b < 8; ++b) acc[b] += hs[b * 64 + lj] * w;
    }

    __shared__ float red[4][8][64];
#pragma unroll
    for (int b = 0; b < 8; ++b) red[jg][b][il] = acc[b];
    __syncthreads();
    for (int u = tx; u < 512; u += 256) {
        int b = u >> 6, ii = u & 63;
        float s = red[0][b][ii] + red[1][b][ii] + red[2][b][ii] + red[3][b][ii];
        part[(size_t)bs * 8192 + b * HH + it * 64 + ii] = s;
    }
}

__global__ void k_mlp_comb(const float* __restrict__ part, int nsplit,
                           const float* __restrict__ resid,
                           const float* __restrict__ bias,
                           float* __restrict__ hout) {
    int idx = blockIdx.x * 256 + threadIdx.x;   // 8192
    if (idx >= BB * HH) return;
    int i = idx & (HH - 1);
    float s = bias[i];
    if (resid) s += resid[idx];
    for (int bs = 0; bs < nsplit; ++bs) s += part[(size_t)bs * 8192 + idx];
    hout[idx] = fmaxf(s, 0.0f);
}

// ---------------- coef projection: split-K ----------------
__global__ void k_coef_part(const float* __restrict__ h,
                            const float* __restrict__ Wx,
                            const float* __restrict__ Wy,
                            const float* __restrict__ Wz,
                            float* __restrict__ cpart) {
    int s = blockIdx.x / COB;
    int blk = blockIdx.x % COB;
    int o = blk * 256 + threadIdx.x;
    if (o >= 3 * BB * KK) return;
    int t = o / (BB * KK);
    int r = o % (BB * KK);
    int b = r / KK, k = r % KK;
    const float* W = (t == 0) ? Wx : ((t == 1) ? Wy : Wz);
    const float* hr = h + b * HH;
    int j0 = s * 128;
    float acc = 0.0f;
#pragma unroll 8
    for (int j = 0; j < 128; ++j) acc += hr[j0 + j] * W[(size_t)(j0 + j) * KK + k];
    cpart[(size_t)s * 7056 + o] = acc;
}

__global__ void k_coef_comb(const float* __restrict__ cpart,
                            const float* __restrict__ bx,
                            const float* __restrict__ by,
                            const float* __restrict__ bz,
                            float* __restrict__ coef) {
    int o = blockIdx.x * 256 + threadIdx.x;
    if (o >= 3 * BB * KK) return;
    int t = o / (BB * KK);
    int k = o % KK;
    float s = ((t == 0) ? bx : ((t == 1) ? by : bz))[k];
#pragma unroll
    for (int i = 0; i < CS; ++i) s += cpart[(size_t)i * 7056 + o];
    coef[o] = s;
}

__global__ void k_reg(const float* __restrict__ coef, float* __restrict__ out_reg) {
    __shared__ float red[256];
    float s = 0.0f;
    for (int i = threadIdx.x; i < 3 * BB * KK; i += 256) {
        float v = coef[i];
        s += v * v;
    }
    red[threadIdx.x] = s;
    __syncthreads();
    for (int off = 128; off > 0; off >>= 1) {
        if ((int)threadIdx.x < off) red[threadIdx.x] += red[threadIdx.x + off];
        __syncthreads();
    }
    if (threadIdx.x == 0) out_reg[0] = 1e-4f * sqrtf(red[0]);
}

// ---------------- flow init, k-split ----------------
__global__ void k_flow_part(const float* __restrict__ coef,
                            const float* __restrict__ Z,
                            float* __restrict__ fpart) {
    int s = blockIdx.x / NB;
    int blk = blockIdx.x % NB;
    int ks = s * FCH;

    __shared__ float sc[24 * FCH];
    for (int u = threadIdx.x; u < 24 * FCH; u += 256) {
        int j = u / FCH, kk = u % FCH;
        int k = ks + kk;
        sc[u] = (k < KK) ? coef[j * KK + k] : 0.0f;
    }
    __syncthreads();

    int n = blk * 256 + threadIdx.x;
    if (n >= NN) return;

    float acc[24];
#pragma unroll
    for (int j = 0; j < 24; ++j) acc[j] = 0.0f;

#pragma unroll 2
    for (int kk = 0; kk < FCH; ++kk) {
        int k = ks + kk;
        int kz = (k < KK) ? k : (KK - 1);
        float z = Z[(size_t)kz * NN + n];
#pragma unroll
        for (int b = 0; b < 8; ++b) {
            acc[b * 3 + 0] += sc[(0 * BB + b) * FCH + kk] * z;
            acc[b * 3 + 1] += sc[(1 * BB + b) * FCH + kk] * z;
            acc[b * 3 + 2] += sc[(2 * BB + b) * FCH + kk] * z;
        }
    }
    float* fr = fpart + (size_t)s * (NN * 24) + (size_t)n * 24;
#pragma unroll
    for (int j = 0; j < 24; ++j) fr[j] = acc[j];
}

__global__ void k_flow_comb(float* __restrict__ fpart) {
    int idx = blockIdx.x * 256 + threadIdx.x;   // NN*6 float4s
    if (idx >= NN * 6) return;
    float4* p0 = (float4*)fpart;
    const float4* p1 = p0 + NN * 6;
    const float4* p2 = p1 + NN * 6;
    const float4* p3 = p2 + NN * 6;
    float4 a = p0[idx], b = p1[idx], c = p2[idx], d = p3[idx];
    float4 r;
    r.x = XS_HALF * (a.x + b.x + c.x + d.x);
    r.y = XS_HALF * (a.y + b.y + c.y + d.y);
    r.z = XS_HALF * (a.z + b.z + c.z + d.z);
    r.w = XS_HALF * (a.w + b.w + c.w + d.w);
    p0[idx] = r;
}

// ---------------- CSR build (by destination) ----------------

__global__ void k_count(const int* __restrict__ ei, int* __restrict__ cnt) {
    int e = blockIdx.x * blockDim.x + threadIdx.x;
    if (e >= EE) return;
    atomicAdd(&cnt[ei[EE + e]], 1);
}

__global__ void k_bsum(const int* __restrict__ cnt, int* __restrict__ bsum) {
    __shared__ int red[256];
    int i = blockIdx.x * 256 + threadIdx.x;
    red[threadIdx.x] = (i < NN) ? cnt[i] : 0;
    __syncthreads();
    for (int off = 128; off > 0; off >>= 1) {
        if ((int)threadIdx.x < off) red[threadIdx.x] += red[threadIdx.x + off];
        __syncthreads();
    }
    if (threadIdx.x == 0) bsum[blockIdx.x] = red[0];
}

__global__ void k_bscan(const int* __restrict__ bsum, int* __restrict__ bpre,
                        int* __restrict__ offs) {
    __shared__ int part[512];
    int t = threadIdx.x;
    part[t] = (t < NB) ? bsum[t] : 0;
    __syncthreads();
    for (int off = 1; off < 512; off <<= 1) {
        int v = (t >= off) ? part[t - off] : 0;
        __syncthreads();
        part[t] += v;
        __syncthreads();
    }
    if (t < NB) bpre[t] = (t == 0) ? 0 : part[t - 1];
    if (t == NB - 1) offs[NN] = part[t];
}

__global__ void k_offs(const int* __restrict__ cnt, const int* __restrict__ bpre,
                       int* __restrict__ offs, int* __restrict__ pos) {
    __shared__ int part[256];
    int t = threadIdx.x;
    int i = blockIdx.x * 256 + t;
    int v = (i < NN) ? cnt[i] : 0;
    part[t] = v;
    __syncthreads();
    for (int off = 1; off < 256; off <<= 1) {
        int u = (t >= off) ? part[t - off] : 0;
        __syncthreads();
        part[t] += u;
        __syncthreads();
    }
    if (i < NN) {
        int ex = bpre[blockIdx.x] + part[t] - v;
        offs[i] = ex;
        pos[i] = ex;
    }
}

// fused payload: one 8B store per edge
__global__ void k_fill(const int* __restrict__ ei, const float* __restrict__ ew,
                       int* __restrict__ pos, int2* __restrict__ csr) {
    int e = blockIdx.x * blockDim.x + threadIdx.x;
    if (e >= EE) return;
    int src = ei[e];
    int dst = ei[EE + e];
    float w = ew[e];
    int p = atomicAdd(&pos[dst], 1);
    int2 v;
    v.x = src;
    v.y = __float_as_int(w);
    csr[p] = v;
}

// invh[n] = 0.5 / max(sum_w, 1e-6)
__global__ void k_degcsr(const int* __restrict__ offs, const int2* __restrict__ csr,
                         float* __restrict__ invh) {
    int n = blockIdx.x * blockDim.x + threadIdx.x;
    if (n >= NN) return;
    int beg = offs[n], end = offs[n + 1];
    float s = 0.0f;
    for (int i = beg; i < end; ++i) s += __int_as_float(csr[i].y);
    invh[n] = 0.5f / fmaxf(s, 1e-6f);
}

// ---------------- diffusion step: fused gather + combine ----------------
__global__ void k_gather(const int* __restrict__ offs, const int2* __restrict__ csr,
                         const float* __restrict__ invh,
                         const float* __restrict__ fin, float* __restrict__ fout) {
    int idx = blockIdx.x * 256 + threadIdx.x;   // NN*6
    if (idx >= NN * 6) return;
    int n = idx / 6;
    int q = idx - n * 6;
    int beg = offs[n], end = offs[n + 1];
    const float4* f4 = (const float4*)fin;
    float4 acc = make_float4(0.f, 0.f, 0.f, 0.f);
    for (int i = beg; i < end; ++i) {
        int2 e = csr[i];
        float w = __int_as_float(e.y);
        float4 fv = f4[(size_t)e.x * 6 + q];
        acc.x += w * fv.x;
        acc.y += w * fv.y;
        acc.z += w * fv.z;
        acc.w += w * fv.w;
    }
    float inv = invh[n];
    float4 fo = f4[(size_t)n * 6 + q];
    float4 r;
    r.x = 0.5f * fo.x + inv * acc.x;
    r.y = 0.5f * fo.y + inv * acc.y;
    r.z = 0.5f * fo.z + inv * acc.z;
    r.w = 0.5f * fo.w + inv * acc.w;
    ((float4*)fout)[(size_t)n * 6 + q] = r;
}

// out[b][n][c] = f[n][b][c], LDS transpose: coalesced both sides
__global__ void k_out(const float* __restrict__ f, float* __restrict__ out) {
    __shared__ float ls[ONODES * 24];
    int n0 = blockIdx.x * ONODES;
    int cnt = NN - n0; if (cnt > ONODES) cnt = ONODES;
    int total = cnt * 24;
    for (int u = threadIdx.x; u < total; u += 256)
        ls[u] = f[(size_t)n0 * 24 + u];
    __syncthreads();
    int per_b = cnt * 3;
    for (int b = 0; b < BB; ++b) {
        for (int u = threadIdx.x; u < per_b; u += 256) {
            int n = u / 3;
            int c = u - 3 * n;
            out[(size_t)b * (NN * 3) + (size_t)n0 * 3 + u] = ls[n * 24 + b * 3 + c];
        }
    }
}

extern "C" void kernel_launch(void* const* d_in, const int* in_sizes, int n_in,
                              void* d_out, int out_size, void* d_ws, size_t ws_size,
                              hipStream_t stream) {
    const float* latent = (const float*)d_in[0];
    const float* W0 = (const float*)d_in[1];
    const float* b0 = (const float*)d_in[2];
    const float* W1 = (const float*)d_in[3];
    const float* b1 = (const float*)d_in[4];
    const float* W2 = (const float*)d_in[5];
    const float* b2 = (const float*)d_in[6];
    const float* W3 = (const float*)d_in[7];
    const float* b3 = (const float*)d_in[8];
    const float* Wx = (const float*)d_in[9];
    const float* bx = (const float*)d_in[10];
    const float* Wy = (const float*)d_in[11];
    const float* by = (const float*)d_in[12];
    const float* Wz = (const float*)d_in[13];
    const float* bz = (const float*)d_in[14];
    const float* Z  = (const float*)d_in[15];
    const float* ew = (const float*)d_in[16];
    const int*   ei = (const int*)d_in[17];
    float* out = (float*)d_out;

    float* p = (float*)d_ws;
    float* h_a     = p; p += 8192;
    float* h_b     = p; p += 8192;
    float* hp      = p; p += 16 * 8192;
    float* coef    = p; p += 7056;
    float* cpart   = p; p += CS * 7056;
    float* invh    = p; p += 100000;
    int*   cnt     = (int*)p; p += 100000;
    int*   offs    = (int*)p; p += 100016;
    int*   pos     = (int*)p; p += 100000;
    int*   bsum    = (int*)p; p += 400;
    int*   bpre    = (int*)p; p += 400;
    int2*  csr     = (int2*)p; p += 2 * 1600000;   // fused {src, w}
    float* fpart   = p; p += (size_t)FS * NN * 24;

    // ---- CSR build ----
    hipMemsetAsync(cnt, 0, NN * sizeof(int), stream);
    k_count<<<(EE + 255) / 256, 256, 0, stream>>>(ei, cnt);
    k_bsum<<<NB, 256, 0, stream>>>(cnt, bsum);
    k_bscan<<<1, 512, 0, stream>>>(bsum, bpre, offs);
    k_offs<<<NB, 256, 0, stream>>>(cnt, bpre, offs, pos);
    k_fill<<<(EE + 255) / 256, 256, 0, stream>>>(ei, ew, pos, csr);
    k_degcsr<<<(NN + 255) / 256, 256, 0, stream>>>(offs, csr, invh);

    // ---- decode MLP (split-K) ----
    k_mlp_part<<<16 * 2, 256, 0, stream>>>(latent, W0, hp, LAT);
    k_mlp_comb<<<32, 256, 0, stream>>>(hp, 2, nullptr, b0, h_a);
    k_mlp_part<<<16 * 16, 256, 0, stream>>>(h_a, W1, hp, HH);
    k_mlp_comb<<<32, 256, 0, stream>>>(hp, 16, h_a, b1, h_b);
    k_mlp_part<<<16 * 16, 256, 0, stream>>>(h_b, W2, hp, HH);
    k_mlp_comb<<<32, 256, 0, stream>>>(hp, 16, h_b, b2, h_a);
    k_mlp_part<<<16 * 16, 256, 0, stream>>>(h_a, W3, hp, HH);
    k_mlp_comb<<<32, 256, 0, stream>>>(hp, 16, h_a, b3, h_b);
    k_coef_part<<<COB * CS, 256, 0, stream>>>(h_b, Wx, Wy, Wz, cpart);
    k_coef_comb<<<COB, 256, 0, stream>>>(cpart, bx, by, bz, coef);
    k_reg<<<1, 256, 0, stream>>>(coef, out + (size_t)BB * NN * 3);

    // ---- flow init (k-split) ----
    k_flow_part<<<NB * FS, 256, 0, stream>>>(coef, Z, fpart);
    k_flow_comb<<<(NN * 6 + 255) / 256, 256, 0, stream>>>(fpart);

    // ---- diffusion ----
    float* f0 = fpart;
    float* f1 = fpart + (size_t)NN * 24;
    float* fc = f0;
    float* fo = f1;
    for (int s = 0; s < NSTEPS; ++s) {
        k_gather<<<(NN * 6 + 255) / 256, 256, 0, stream>>>(offs, csr, invh, fc, fo);
        float* t = fc; fc = fo; fo = t;
    }

    k_out<<<(NN + ONODES - 1) / ONODES, 256, 0, stream>>>(fc, out);
}

// Round 6
// 635.363 us; speedup vs baseline: 1.0633x; 1.0633x over previous
//
#include <hip/hip_runtime.h>
#include <math.h>

#define BB 8
#define LAT 128
#define HH 1024
#define KK 294
#define NN 100000
#define EE 1600000
#define NSTEPS 3
#define XS_HALF 64.0f

#define NB 391      // ceil(NN/256)
#define FS 4        // flow_init k-splits
#define FCH 74      // ceil(294/4)
#define CS 8        // coef j-splits (128 each)
#define COB 28      // ceil(7056/256)
#define ONODES 512  // k_out nodes per block
#define ES 400128   // edge batch stride = 1563*256 (4 edges/thread)
#define EBLK 1563   // edge blocks

// ---------------- device bodies ----------------

__device__ __forceinline__ void mlp_part_body(int bid, const float* __restrict__ hin,
                                              const float* __restrict__ W,
                                              float* __restrict__ part, int jdim) {
    int it = bid & 15;
    int bs = bid >> 4;
    int tx = threadIdx.x;
    int il = tx & 63;
    int jg = tx >> 6;
    int i = it * 64 + il;
    int j0 = bs * 64;

    __shared__ float hs[8 * 64];
    for (int u = tx; u < 512; u += 256) {
        int b = u >> 6, lj = u & 63;
        hs[u] = hin[b * jdim + j0 + lj];
    }
    __syncthreads();

    float acc[8];
#pragma unroll
    for (int b = 0; b < 8; ++b) acc[b] = 0.0f;
#pragma unroll
    for (int jj = 0; jj < 16; ++jj) {
        int lj = jg * 16 + jj;
        float w = W[(size_t)(j0 + lj) * HH + i];
#pragma unroll
        for (int b = 0; b < 8; ++b) acc[b] += hs[b * 64 + lj] * w;
    }

    __shared__ float red[4][8][64];
#pragma unroll
    for (int b = 0; b < 8; ++b) red[jg][b][il] = acc[b];
    __syncthreads();
    for (int u = tx; u < 512; u += 256) {
        int b = u >> 6, ii = u & 63;
        float s = red[0][b][ii] + red[1][b][ii] + red[2][b][ii] + red[3][b][ii];
        part[(size_t)bs * 8192 + b * HH + it * 64 + ii] = s;
    }
}

__device__ __forceinline__ void mlp_comb_body(int bid, const float* __restrict__ part,
                                              int nsplit, const float* __restrict__ resid,
                                              const float* __restrict__ bias,
                                              float* __restrict__ hout) {
    int idx = bid * 256 + threadIdx.x;
    if (idx >= BB * HH) return;
    int i = idx & (HH - 1);
    float s = bias[i];
    if (resid) s += resid[idx];
    for (int bs = 0; bs < nsplit; ++bs) s += part[(size_t)bs * 8192 + idx];
    hout[idx] = fmaxf(s, 0.0f);
}

__device__ __forceinline__ void count_body(int bid, const int* __restrict__ ei,
                                           int* __restrict__ cnt) {
    int gid = bid * 256 + threadIdx.x;
    int d0 = ei[EE + gid];
    int d1 = ei[EE + gid + ES];
    int d2 = ei[EE + gid + 2 * ES];
    bool v3 = (gid + 3 * ES) < EE;
    int d3 = v3 ? ei[EE + gid + 3 * ES] : 0;
    atomicAdd(&cnt[d0], 1);
    atomicAdd(&cnt[d1], 1);
    atomicAdd(&cnt[d2], 1);
    if (v3) atomicAdd(&cnt[d3], 1);
}

__device__ __forceinline__ void bsum_body(int bid, const int* __restrict__ cnt,
                                          int* __restrict__ bsum) {
    __shared__ int red[256];
    int i = bid * 256 + threadIdx.x;
    red[threadIdx.x] = (i < NN) ? cnt[i] : 0;
    __syncthreads();
    for (int off = 128; off > 0; off >>= 1) {
        if ((int)threadIdx.x < off) red[threadIdx.x] += red[threadIdx.x + off];
        __syncthreads();
    }
    if (threadIdx.x == 0) bsum[bid] = red[0];
}

// 256 threads scan NB(<=512) values, double-buffered
__device__ __forceinline__ void bscan_body(const int* __restrict__ bsum,
                                           int* __restrict__ bpre,
                                           int* __restrict__ offs) {
    __shared__ int A[512], Bf[512];
    int t = threadIdx.x;
    A[t] = (t < NB) ? bsum[t] : 0;
    A[t + 256] = (t + 256 < NB) ? bsum[t + 256] : 0;
    __syncthreads();
    int* s = A;
    int* d = Bf;
    for (int off = 1; off < 512; off <<= 1) {
        d[t] = s[t] + ((t >= off) ? s[t - off] : 0);
        int u = t + 256;
        d[u] = s[u] + ((u >= off) ? s[u - off] : 0);
        __syncthreads();
        int* tmp = s; s = d; d = tmp;
    }
    if (t < NB) bpre[t] = (t == 0) ? 0 : s[t - 1];
    int u = t + 256;
    if (u < NB) bpre[u] = s[u - 1];
    if (t == 0) offs[NN] = s[NB - 1];
}

__device__ __forceinline__ void offs_body(int bid, const int* __restrict__ cnt,
                                          const int* __restrict__ bpre,
                                          int* __restrict__ offs, int* __restrict__ pos) {
    __shared__ int part[256];
    int t = threadIdx.x;
    int i = bid * 256 + t;
    int v = (i < NN) ? cnt[i] : 0;
    part[t] = v;
    __syncthreads();
    for (int off = 1; off < 256; off <<= 1) {
        int u = (t >= off) ? part[t - off] : 0;
        __syncthreads();
        part[t] += u;
        __syncthreads();
    }
    if (i < NN) {
        int ex = bpre[bid] + part[t] - v;
        offs[i] = ex;
        pos[i] = ex;
    }
}

__device__ __forceinline__ void fill_body(int bid, const int* __restrict__ ei,
                                          const float* __restrict__ ew,
                                          int* __restrict__ pos,
                                          int* __restrict__ csr_src,
                                          float* __restrict__ csr_w) {
    int gid = bid * 256 + threadIdx.x;
    int e0 = gid, e1 = gid + ES, e2 = gid + 2 * ES, e3 = gid + 3 * ES;
    bool v3 = e3 < EE;
    int s0 = ei[e0], s1 = ei[e1], s2 = ei[e2];
    int d0 = ei[EE + e0], d1 = ei[EE + e1], d2 = ei[EE + e2];
    float w0 = ew[e0], w1 = ew[e1], w2 = ew[e2];
    int s3 = 0, d3 = 0; float w3 = 0.0f;
    if (v3) { s3 = ei[e3]; d3 = ei[EE + e3]; w3 = ew[e3]; }
    int p0 = atomicAdd(&pos[d0], 1);
    int p1 = atomicAdd(&pos[d1], 1);
    int p2 = atomicAdd(&pos[d2], 1);
    int p3 = v3 ? atomicAdd(&pos[d3], 1) : 0;
    csr_src[p0] = s0; csr_w[p0] = w0;
    csr_src[p1] = s1; csr_w[p1] = w1;
    csr_src[p2] = s2; csr_w[p2] = w2;
    if (v3) { csr_src[p3] = s3; csr_w[p3] = w3; }
}

__device__ __forceinline__ void degcsr_body(int bid, const int* __restrict__ offs,
                                            const float* __restrict__ csr_w,
                                            float* __restrict__ invh) {
    int n = bid * 256 + threadIdx.x;
    if (n >= NN) return;
    int beg = offs[n], end = offs[n + 1];
    float s = 0.0f;
    for (int i = beg; i < end; ++i) s += csr_w[i];
    invh[n] = 0.5f / fmaxf(s, 1e-6f);
}

__device__ __forceinline__ void flow_part_body(int bid, const float* __restrict__ coef,
                                               const float* __restrict__ Z,
                                               float* __restrict__ fpart) {
    int s = bid / NB;
    int blk = bid % NB;
    int ks = s * FCH;

    __shared__ float sc[24 * FCH];
    for (int u = threadIdx.x; u < 24 * FCH; u += 256) {
        int j = u / FCH, kk = u % FCH;
        int k = ks + kk;
        sc[u] = (k < KK) ? coef[j * KK + k] : 0.0f;
    }
    __syncthreads();

    int n = blk * 256 + threadIdx.x;
    if (n >= NN) return;

    float acc[24];
#pragma unroll
    for (int j = 0; j < 24; ++j) acc[j] = 0.0f;

#pragma unroll 2
    for (int kk = 0; kk < FCH; ++kk) {
        int k = ks + kk;
        int kz = (k < KK) ? k : (KK - 1);
        float z = Z[(size_t)kz * NN + n];
#pragma unroll
        for (int b = 0; b < 8; ++b) {
            acc[b * 3 + 0] += sc[(0 * BB + b) * FCH + kk] * z;
            acc[b * 3 + 1] += sc[(1 * BB + b) * FCH + kk] * z;
            acc[b * 3 + 2] += sc[(2 * BB + b) * FCH + kk] * z;
        }
    }
    float* fr = fpart + (size_t)s * (NN * 24) + (size_t)n * 24;
#pragma unroll
    for (int j = 0; j < 24; ++j) fr[j] = acc[j];
}

__device__ __forceinline__ void flow_comb_body(int bid, float* __restrict__ fpart) {
    int idx = bid * 256 + threadIdx.x;
    if (idx >= NN * 6) return;
    float4* p0 = (float4*)fpart;
    const float4* p1 = p0 + NN * 6;
    const float4* p2 = p1 + NN * 6;
    const float4* p3 = p2 + NN * 6;
    float4 a = p0[idx], b = p1[idx], c = p2[idx], d = p3[idx];
    float4 r;
    r.x = XS_HALF * (a.x + b.x + c.x + d.x);
    r.y = XS_HALF * (a.y + b.y + c.y + d.y);
    r.z = XS_HALF * (a.z + b.z + c.z + d.z);
    r.w = XS_HALF * (a.w + b.w + c.w + d.w);
    p0[idx] = r;
}

__device__ __forceinline__ void reg_body(const float* __restrict__ coef,
                                         float* __restrict__ out_reg) {
    __shared__ float red[256];
    float s = 0.0f;
    for (int i = threadIdx.x; i < 3 * BB * KK; i += 256) {
        float v = coef[i];
        s += v * v;
    }
    red[threadIdx.x] = s;
    __syncthreads();
    for (int off = 128; off > 0; off >>= 1) {
        if ((int)threadIdx.x < off) red[threadIdx.x] += red[threadIdx.x + off];
        __syncthreads();
    }
    if (threadIdx.x == 0) out_reg[0] = 1e-4f * sqrtf(red[0]);
}

// ---------------- fused kernels ----------------

__global__ void K1_mlp0_count(const float* __restrict__ latent, const float* __restrict__ W0,
                              float* __restrict__ part, const int* __restrict__ ei,
                              int* __restrict__ cnt) {
    if (blockIdx.x < 32) mlp_part_body(blockIdx.x, latent, W0, part, LAT);
    else count_body(blockIdx.x - 32, ei, cnt);
}

__global__ void K2_comb0_bsum(const float* __restrict__ part, const float* __restrict__ b0,
                              float* __restrict__ hout, const int* __restrict__ cnt,
                              int* __restrict__ bsum) {
    if (blockIdx.x < 32) mlp_comb_body(blockIdx.x, part, 2, nullptr, b0, hout);
    else bsum_body(blockIdx.x - 32, cnt, bsum);
}

__global__ void K3_bscan_mlp1(const int* __restrict__ bsum, int* __restrict__ bpre,
                              int* __restrict__ offs, const float* __restrict__ hin,
                              const float* __restrict__ W1, float* __restrict__ part) {
    if (blockIdx.x == 0) bscan_body(bsum, bpre, offs);
    else mlp_part_body(blockIdx.x - 1, hin, W1, part, HH);
}

__global__ void K4_comb1_offs(const float* __restrict__ part, const float* __restrict__ resid,
                              const float* __restrict__ b1, float* __restrict__ hout,
                              const int* __restrict__ cnt, const int* __restrict__ bpre,
                              int* __restrict__ offs, int* __restrict__ pos) {
    if (blockIdx.x < 32) mlp_comb_body(blockIdx.x, part, 16, resid, b1, hout);
    else offs_body(blockIdx.x - 32, cnt, bpre, offs, pos);
}

__global__ void K_mlp_part(const float* __restrict__ hin, const float* __restrict__ W,
                           float* __restrict__ part) {
    mlp_part_body(blockIdx.x, hin, W, part, HH);
}

__global__ void K_mlp_comb(const float* __restrict__ part, const float* __restrict__ resid,
                           const float* __restrict__ bias, float* __restrict__ hout) {
    mlp_comb_body(blockIdx.x, part, 16, resid, bias, hout);
}

__global__ void k_coef_part(const float* __restrict__ h,
                            const float* __restrict__ Wx,
                            const float* __restrict__ Wy,
                            const float* __restrict__ Wz,
                            float* __restrict__ cpart) {
    int s = blockIdx.x / COB;
    int blk = blockIdx.x % COB;
    int o = blk * 256 + threadIdx.x;
    if (o >= 3 * BB * KK) return;
    int t = o / (BB * KK);
    int r = o % (BB * KK);
    int b = r / KK, k = r % KK;
    const float* W = (t == 0) ? Wx : ((t == 1) ? Wy : Wz);
    const float* hr = h + b * HH;
    int j0 = s * 128;
    float acc = 0.0f;
#pragma unroll 8
    for (int j = 0; j < 128; ++j) acc += hr[j0 + j] * W[(size_t)(j0 + j) * KK + k];
    cpart[(size_t)s * 7056 + o] = acc;
}

__global__ void k_coef_comb(const float* __restrict__ cpart,
                            const float* __restrict__ bx,
                            const float* __restrict__ by,
                            const float* __restrict__ bz,
                            float* __restrict__ coef) {
    int o = blockIdx.x * 256 + threadIdx.x;
    if (o >= 3 * BB * KK) return;
    int t = o / (BB * KK);
    int k = o % KK;
    float s = ((t == 0) ? bx : ((t == 1) ? by : bz))[k];
#pragma unroll
    for (int i = 0; i < CS; ++i) s += cpart[(size_t)i * 7056 + o];
    coef[o] = s;
}

// flow_part (NB*FS blocks) + fill (EBLK blocks) + reg (1 block)
__global__ void K11_flow_fill_reg(const float* __restrict__ coef, const float* __restrict__ Z,
                                  float* __restrict__ fpart, const int* __restrict__ ei,
                                  const float* __restrict__ ew, int* __restrict__ pos,
                                  int* __restrict__ csr_src, float* __restrict__ csr_w,
                                  float* __restrict__ out_reg) {
    if (blockIdx.x < NB * FS) flow_part_body(blockIdx.x, coef, Z, fpart);
    else if (blockIdx.x < NB * FS + EBLK) fill_body(blockIdx.x - NB * FS, ei, ew, pos, csr_src, csr_w);
    else reg_body(coef, out_reg);
}

__global__ void K12_fcomb_deg(float* __restrict__ fpart, const int* __restrict__ offs,
                              const float* __restrict__ csr_w, float* __restrict__ invh) {
    if (blockIdx.x < 2344) flow_comb_body(blockIdx.x, fpart);
    else degcsr_body(blockIdx.x - 2344, offs, csr_w, invh);
}

// ---------------- diffusion step: fused gather + combine ----------------
__global__ void k_gather(const int* __restrict__ offs, const int* __restrict__ csr_src,
                         const float* __restrict__ csr_w, const float* __restrict__ invh,
                         const float* __restrict__ fin, float* __restrict__ fout) {
    int idx = blockIdx.x * 256 + threadIdx.x;   // NN*6
    if (idx >= NN * 6) return;
    int n = idx / 6;
    int q = idx - n * 6;
    int beg = offs[n], end = offs[n + 1];
    const float4* f4 = (const float4*)fin;
    float4 acc = make_float4(0.f, 0.f, 0.f, 0.f);
    for (int i = beg; i < end; ++i) {
        int s = csr_src[i];
        float w = csr_w[i];
        float4 fv = f4[(size_t)s * 6 + q];
        acc.x += w * fv.x;
        acc.y += w * fv.y;
        acc.z += w * fv.z;
        acc.w += w * fv.w;
    }
    float inv = invh[n];
    float4 fo = f4[(size_t)n * 6 + q];
    float4 r;
    r.x = 0.5f * fo.x + inv * acc.x;
    r.y = 0.5f * fo.y + inv * acc.y;
    r.z = 0.5f * fo.z + inv * acc.z;
    r.w = 0.5f * fo.w + inv * acc.w;
    ((float4*)fout)[(size_t)n * 6 + q] = r;
}

// out[b][n][c] = f[n][b][c], LDS transpose
__global__ void k_out(const float* __restrict__ f, float* __restrict__ out) {
    __shared__ float ls[ONODES * 24];
    int n0 = blockIdx.x * ONODES;
    int cnt = NN - n0; if (cnt > ONODES) cnt = ONODES;
    int total = cnt * 24;
    for (int u = threadIdx.x; u < total; u += 256)
        ls[u] = f[(size_t)n0 * 24 + u];
    __syncthreads();
    int per_b = cnt * 3;
    for (int b = 0; b < BB; ++b) {
        for (int u = threadIdx.x; u < per_b; u += 256) {
            int n = u / 3;
            int c = u - 3 * n;
            out[(size_t)b * (NN * 3) + (size_t)n0 * 3 + u] = ls[n * 24 + b * 3 + c];
        }
    }
}

extern "C" void kernel_launch(void* const* d_in, const int* in_sizes, int n_in,
                              void* d_out, int out_size, void* d_ws, size_t ws_size,
                              hipStream_t stream) {
    const float* latent = (const float*)d_in[0];
    const float* W0 = (const float*)d_in[1];
    const float* b0 = (const float*)d_in[2];
    const float* W1 = (const float*)d_in[3];
    const float* b1 = (const float*)d_in[4];
    const float* W2 = (const float*)d_in[5];
    const float* b2 = (const float*)d_in[6];
    const float* W3 = (const float*)d_in[7];
    const float* b3 = (const float*)d_in[8];
    const float* Wx = (const float*)d_in[9];
    const float* bx = (const float*)d_in[10];
    const float* Wy = (const float*)d_in[11];
    const float* by = (const float*)d_in[12];
    const float* Wz = (const float*)d_in[13];
    const float* bz = (const float*)d_in[14];
    const float* Z  = (const float*)d_in[15];
    const float* ew = (const float*)d_in[16];
    const int*   ei = (const int*)d_in[17];
    float* out = (float*)d_out;

    float* p = (float*)d_ws;
    float* h_a     = p; p += 8192;
    float* h_b     = p; p += 8192;
    float* hp      = p; p += 16 * 8192;
    float* coef    = p; p += 7056;
    float* cpart   = p; p += CS * 7056;
    float* invh    = p; p += 100000;
    int*   cnt     = (int*)p; p += 100000;
    int*   offs    = (int*)p; p += 100016;
    int*   pos     = (int*)p; p += 100000;
    int*   bsum    = (int*)p; p += 512;
    int*   bpre    = (int*)p; p += 512;
    int*   csr_src = (int*)p; p += 1600000;
    float* csr_w   = p; p += 1600000;
    float* fpart   = p; p += (size_t)FS * NN * 24;

    hipMemsetAsync(cnt, 0, NN * sizeof(int), stream);

    // MLP layer 0 + edge count
    K1_mlp0_count<<<32 + EBLK, 256, 0, stream>>>(latent, W0, hp, ei, cnt);
    // comb0 + block sums
    K2_comb0_bsum<<<32 + NB, 256, 0, stream>>>(hp, b0, h_a, cnt, bsum);
    // block-sum scan + MLP layer 1
    K3_bscan_mlp1<<<1 + 256, 256, 0, stream>>>(bsum, bpre, offs, h_a, W1, hp);
    // comb1 + final offsets
    K4_comb1_offs<<<32 + NB, 256, 0, stream>>>(hp, h_a, b1, h_b, cnt, bpre, offs, pos);
    // MLP layers 2,3
    K_mlp_part<<<256, 256, 0, stream>>>(h_b, W2, hp);
    K_mlp_comb<<<32, 256, 0, stream>>>(hp, h_b, b2, h_a);
    K_mlp_part<<<256, 256, 0, stream>>>(h_a, W3, hp);
    K_mlp_comb<<<32, 256, 0, stream>>>(hp, h_a, b3, h_b);
    // coef projection
    k_coef_part<<<COB * CS, 256, 0, stream>>>(h_b, Wx, Wy, Wz, cpart);
    k_coef_comb<<<COB, 256, 0, stream>>>(cpart, bx, by, bz, coef);
    // flow partials + CSR fill + reg (all independent)
    K11_flow_fill_reg<<<NB * FS + EBLK + 1, 256, 0, stream>>>(coef, Z, fpart, ei, ew, pos,
                                                              csr_src, csr_w,
                                                              out + (size_t)BB * NN * 3);
    // flow combine + inverse degree
    K12_fcomb_deg<<<2344 + NB, 256, 0, stream>>>(fpart, offs, csr_w, invh);

    // diffusion
    float* f0 = fpart;
    float* f1 = fpart + (size_t)NN * 24;
    float* fc = f0;
    float* fo = f1;
    for (int s = 0; s < NSTEPS; ++s) {
        k_gather<<<(NN * 6 + 255) / 256, 256, 0, stream>>>(offs, csr_src, csr_w, invh, fc, fo);
        float* t = fc; fc = fo; fo = t;
    }

    k_out<<<(NN + ONODES - 1) / ONODES, 256, 0, stream>>>(fc, out);
}

// Round 8
// 573.076 us; speedup vs baseline: 1.1789x; 1.1087x over previous
//
#include <hip/hip_runtime.h>
#include <math.h>

#define BB 8
#define LAT 128
#define HH 1024
#define KK 294
#define NN 100000
#define EE 1600000
#define NSTEPS 3
#define XS_HALF 64.0f

#define NB 391      // ceil(NN/256)
#define FS 4        // flow_init k-splits
#define FCH 74      // ceil(294/4)
#define CS 8        // coef j-splits (128 each)
#define COB 28      // ceil(7056/256)
#define EPT 8       // edges per thread
#define EST 200000  // EE/EPT
#define EBLK 782    // ceil(EST/256)
#define GON 40      // nodes per block in gather_out

// ---------------- device bodies ----------------

__device__ __forceinline__ void mlp_part_body(int bid, const float* __restrict__ hin,
                                              const float* __restrict__ W,
                                              float* __restrict__ part, int jdim) {
    int it = bid & 15;
    int bs = bid >> 4;
    int tx = threadIdx.x;
    int il = tx & 63;
    int jg = tx >> 6;
    int i = it * 64 + il;
    int j0 = bs * 64;

    __shared__ float hs[8 * 64];
    for (int u = tx; u < 512; u += 256) {
        int b = u >> 6, lj = u & 63;
        hs[u] = hin[b * jdim + j0 + lj];
    }
    __syncthreads();

    float acc[8];
#pragma unroll
    for (int b = 0; b < 8; ++b) acc[b] = 0.0f;
#pragma unroll
    for (int jj = 0; jj < 16; ++jj) {
        int lj = jg * 16 + jj;
        float w = W[(size_t)(j0 + lj) * HH + i];
#pragma unroll
        for (int b = 0; b < 8; ++b) acc[b] += hs[b * 64 + lj] * w;
    }

    __shared__ float red[4][8][64];
#pragma unroll
    for (int b = 0; b < 8; ++b) red[jg][b][il] = acc[b];
    __syncthreads();
    for (int u = tx; u < 512; u += 256) {
        int b = u >> 6, ii = u & 63;
        float s = red[0][b][ii] + red[1][b][ii] + red[2][b][ii] + red[3][b][ii];
        part[(size_t)bs * 8192 + b * HH + it * 64 + ii] = s;
    }
}

__device__ __forceinline__ void mlp_comb_body(int bid, const float* __restrict__ part,
                                              int nsplit, const float* __restrict__ resid,
                                              const float* __restrict__ bias,
                                              float* __restrict__ hout) {
    int idx = bid * 256 + threadIdx.x;
    if (idx >= BB * HH) return;
    int i = idx & (HH - 1);
    float s = bias[i];
    if (resid) s += resid[idx];
    for (int bs = 0; bs < nsplit; ++bs) s += part[(size_t)bs * 8192 + idx];
    hout[idx] = fmaxf(s, 0.0f);
}

// count + capture rank (one atomic per edge, batched 8/thread)
__device__ __forceinline__ void count_body(int bid, const int* __restrict__ ei,
                                           int* __restrict__ cnt, int* __restrict__ rank) {
    int gid = bid * 256 + threadIdx.x;
    if (gid >= EST) return;
    int d[EPT];
#pragma unroll
    for (int j = 0; j < EPT; ++j) d[j] = ei[EE + gid + j * EST];
#pragma unroll
    for (int j = 0; j < EPT; ++j) {
        int p = atomicAdd(&cnt[d[j]], 1);
        rank[gid + j * EST] = p;
    }
}

__device__ __forceinline__ void bsum_body(int bid, const int* __restrict__ cnt,
                                          int* __restrict__ bsum) {
    __shared__ int red[256];
    int i = bid * 256 + threadIdx.x;
    red[threadIdx.x] = (i < NN) ? cnt[i] : 0;
    __syncthreads();
    for (int off = 128; off > 0; off >>= 1) {
        if ((int)threadIdx.x < off) red[threadIdx.x] += red[threadIdx.x + off];
        __syncthreads();
    }
    if (threadIdx.x == 0) bsum[bid] = red[0];
}

__device__ __forceinline__ void bscan_body(const int* __restrict__ bsum,
                                           int* __restrict__ bpre,
                                           int* __restrict__ offs) {
    __shared__ int A[512], Bf[512];
    int t = threadIdx.x;
    A[t] = (t < NB) ? bsum[t] : 0;
    A[t + 256] = (t + 256 < NB) ? bsum[t + 256] : 0;
    __syncthreads();
    int* s = A;
    int* d = Bf;
    for (int off = 1; off < 512; off <<= 1) {
        d[t] = s[t] + ((t >= off) ? s[t - off] : 0);
        int u = t + 256;
        d[u] = s[u] + ((u >= off) ? s[u - off] : 0);
        __syncthreads();
        int* tmp = s; s = d; d = tmp;
    }
    if (t < NB) bpre[t] = (t == 0) ? 0 : s[t - 1];
    int u = t + 256;
    if (u < NB) bpre[u] = s[u - 1];
    if (t == 0) offs[NN] = s[NB - 1];
}

__device__ __forceinline__ void offs_body(int bid, const int* __restrict__ cnt,
                                          const int* __restrict__ bpre,
                                          int* __restrict__ offs) {
    __shared__ int part[256];
    int t = threadIdx.x;
    int i = bid * 256 + t;
    int v = (i < NN) ? cnt[i] : 0;
    part[t] = v;
    __syncthreads();
    for (int off = 1; off < 256; off <<= 1) {
        int u = (t >= off) ? part[t - off] : 0;
        __syncthreads();
        part[t] += u;
        __syncthreads();
    }
    if (i < NN) offs[i] = bpre[bid] + part[t] - v;
}

// atomic-free fill: p = offs[dst] + rank[e]
__device__ __forceinline__ void fill_body(int bid, const int* __restrict__ ei,
                                          const float* __restrict__ ew,
                                          const int* __restrict__ offs,
                                          const int* __restrict__ rank,
                                          int2* __restrict__ csr) {
    int gid = bid * 256 + threadIdx.x;
    if (gid >= EST) return;
    int s[EPT], d[EPT], r[EPT];
    float w[EPT];
#pragma unroll
    for (int j = 0; j < EPT; ++j) {
        int e = gid + j * EST;
        s[j] = ei[e];
        d[j] = ei[EE + e];
        w[j] = ew[e];
        r[j] = rank[e];
    }
#pragma unroll
    for (int j = 0; j < EPT; ++j) {
        int p = offs[d[j]] + r[j];
        int2 v;
        v.x = s[j];
        v.y = __float_as_int(w[j]);
        csr[p] = v;
    }
}

__device__ __forceinline__ void degcsr_body(int bid, const int* __restrict__ offs,
                                            const int2* __restrict__ csr,
                                            float* __restrict__ invh) {
    int n = bid * 256 + threadIdx.x;
    if (n >= NN) return;
    int beg = offs[n], end = offs[n + 1];
    float s = 0.0f;
    for (int i = beg; i < end; ++i) s += __int_as_float(csr[i].y);
    invh[n] = 0.5f / fmaxf(s, 1e-6f);
}

__device__ __forceinline__ void flow_part_body(int bid, const float* __restrict__ coef,
                                               const float* __restrict__ Z,
                                               float* __restrict__ fpart) {
    int s = bid / NB;
    int blk = bid % NB;
    int ks = s * FCH;

    __shared__ float sc[24 * FCH];
    for (int u = threadIdx.x; u < 24 * FCH; u += 256) {
        int j = u / FCH, kk = u % FCH;
        int k = ks + kk;
        sc[u] = (k < KK) ? coef[j * KK + k] : 0.0f;
    }
    __syncthreads();

    int n = blk * 256 + threadIdx.x;
    if (n >= NN) return;

    float acc[24];
#pragma unroll
    for (int j = 0; j < 24; ++j) acc[j] = 0.0f;

#pragma unroll 2
    for (int kk = 0; kk < FCH; ++kk) {
        int k = ks + kk;
        int kz = (k < KK) ? k : (KK - 1);
        float z = Z[(size_t)kz * NN + n];
#pragma unroll
        for (int b = 0; b < 8; ++b) {
            acc[b * 3 + 0] += sc[(0 * BB + b) * FCH + kk] * z;
            acc[b * 3 + 1] += sc[(1 * BB + b) * FCH + kk] * z;
            acc[b * 3 + 2] += sc[(2 * BB + b) * FCH + kk] * z;
        }
    }
    float* fr = fpart + (size_t)s * (NN * 24) + (size_t)n * 24;
#pragma unroll
    for (int j = 0; j < 24; ++j) fr[j] = acc[j];
}

__device__ __forceinline__ void flow_comb_body(int bid, float* __restrict__ fpart) {
    int idx = bid * 256 + threadIdx.x;
    if (idx >= NN * 6) return;
    float4* p0 = (float4*)fpart;
    const float4* p1 = p0 + NN * 6;
    const float4* p2 = p1 + NN * 6;
    const float4* p3 = p2 + NN * 6;
    float4 a = p0[idx], b = p1[idx], c = p2[idx], d = p3[idx];
    float4 r;
    r.x = XS_HALF * (a.x + b.x + c.x + d.x);
    r.y = XS_HALF * (a.y + b.y + c.y + d.y);
    r.z = XS_HALF * (a.z + b.z + c.z + d.z);
    r.w = XS_HALF * (a.w + b.w + c.w + d.w);
    p0[idx] = r;
}

__device__ __forceinline__ void reg_body(const float* __restrict__ coef,
                                         float* __restrict__ out_reg) {
    __shared__ float red[256];
    float s = 0.0f;
    for (int i = threadIdx.x; i < 3 * BB * KK; i += 256) {
        float v = coef[i];
        s += v * v;
    }
    red[threadIdx.x] = s;
    __syncthreads();
    for (int off = 128; off > 0; off >>= 1) {
        if ((int)threadIdx.x < off) red[threadIdx.x] += red[threadIdx.x + off];
        __syncthreads();
    }
    if (threadIdx.x == 0) out_reg[0] = 1e-4f * sqrtf(red[0]);
}

// ---------------- fused kernels ----------------

__global__ void K1_mlp0_count(const float* __restrict__ latent, const float* __restrict__ W0,
                              float* __restrict__ part, const int* __restrict__ ei,
                              int* __restrict__ cnt, int* __restrict__ rank) {
    if (blockIdx.x < 32) mlp_part_body(blockIdx.x, latent, W0, part, LAT);
    else count_body(blockIdx.x - 32, ei, cnt, rank);
}

__global__ void K2_comb0_bsum(const float* __restrict__ part, const float* __restrict__ b0,
                              float* __restrict__ hout, const int* __restrict__ cnt,
                              int* __restrict__ bsum) {
    if (blockIdx.x < 32) mlp_comb_body(blockIdx.x, part, 2, nullptr, b0, hout);
    else bsum_body(blockIdx.x - 32, cnt, bsum);
}

__global__ void K3_bscan_mlp1(const int* __restrict__ bsum, int* __restrict__ bpre,
                              int* __restrict__ offs, const float* __restrict__ hin,
                              const float* __restrict__ W1, float* __restrict__ part) {
    if (blockIdx.x == 0) bscan_body(bsum, bpre, offs);
    else mlp_part_body(blockIdx.x - 1, hin, W1, part, HH);
}

__global__ void K4_comb1_offs(const float* __restrict__ part, const float* __restrict__ resid,
                              const float* __restrict__ b1, float* __restrict__ hout,
                              const int* __restrict__ cnt, const int* __restrict__ bpre,
                              int* __restrict__ offs) {
    if (blockIdx.x < 32) mlp_comb_body(blockIdx.x, part, 16, resid, b1, hout);
    else offs_body(blockIdx.x - 32, cnt, bpre, offs);
}

// MLP layer 2 part + CSR fill (both independent): fill starts as early as offs exists
__global__ void K5_mlp2_fill(const float* __restrict__ hin, const float* __restrict__ W2,
                             float* __restrict__ part, const int* __restrict__ ei,
                             const float* __restrict__ ew, const int* __restrict__ offs,
                             const int* __restrict__ rank, int2* __restrict__ csr) {
    if (blockIdx.x < 256) mlp_part_body(blockIdx.x, hin, W2, part, HH);
    else fill_body(blockIdx.x - 256, ei, ew, offs, rank, csr);
}

__global__ void K6_comb2_deg(const float* __restrict__ part, const float* __restrict__ resid,
                             const float* __restrict__ bias, float* __restrict__ hout,
                             const int* __restrict__ offs, const int2* __restrict__ csr,
                             float* __restrict__ invh) {
    if (blockIdx.x < 32) mlp_comb_body(blockIdx.x, part, 16, resid, bias, hout);
    else degcsr_body(blockIdx.x - 32, offs, csr, invh);
}

__global__ void K_mlp_part3(const float* __restrict__ hin, const float* __restrict__ W,
                            float* __restrict__ part) {
    mlp_part_body(blockIdx.x, hin, W, part, HH);
}

__global__ void K_mlp_comb(const float* __restrict__ part, const float* __restrict__ resid,
                           const float* __restrict__ bias, float* __restrict__ hout) {
    mlp_comb_body(blockIdx.x, part, 16, resid, bias, hout);
}

__global__ void k_coef_part(const float* __restrict__ h,
                            const float* __restrict__ Wx,
                            const float* __restrict__ Wy,
                            const float* __restrict__ Wz,
                            float* __restrict__ cpart) {
    int s = blockIdx.x / COB;
    int blk = blockIdx.x % COB;
    int o = blk * 256 + threadIdx.x;
    if (o >= 3 * BB * KK) return;
    int t = o / (BB * KK);
    int r = o % (BB * KK);
    int b = r / KK, k = r % KK;
    const float* W = (t == 0) ? Wx : ((t == 1) ? Wy : Wz);
    const float* hr = h + b * HH;
    int j0 = s * 128;
    float acc = 0.0f;
#pragma unroll 8
    for (int j = 0; j < 128; ++j) acc += hr[j0 + j] * W[(size_t)(j0 + j) * KK + k];
    cpart[(size_t)s * 7056 + o] = acc;
}

__global__ void k_coef_comb(const float* __restrict__ cpart,
                            const float* __restrict__ bx,
                            const float* __restrict__ by,
                            const float* __restrict__ bz,
                            float* __restrict__ coef) {
    int o = blockIdx.x * 256 + threadIdx.x;
    if (o >= 3 * BB * KK) return;
    int t = o / (BB * KK);
    int k = o % KK;
    float s = ((t == 0) ? bx : ((t == 1) ? by : bz))[k];
#pragma unroll
    for (int i = 0; i < CS; ++i) s += cpart[(size_t)i * 7056 + o];
    coef[o] = s;
}

// flow partials + reg
__global__ void K11_flow_reg(const float* __restrict__ coef, const float* __restrict__ Z,
                             float* __restrict__ fpart, float* __restrict__ out_reg) {
    if (blockIdx.x < NB * FS) flow_part_body(blockIdx.x, coef, Z, fpart);
    else reg_body(coef, out_reg);
}

__global__ void K12_fcomb(float* __restrict__ fpart) {
    flow_comb_body(blockIdx.x, fpart);
}

// ---------------- diffusion ----------------
__global__ void k_gather(const int* __restrict__ offs, const int2* __restrict__ csr,
                         const float* __restrict__ invh,
                         const float* __restrict__ fin, float* __restrict__ fout) {
    int idx = blockIdx.x * 256 + threadIdx.x;   // NN*6
    if (idx >= NN * 6) return;
    int n = idx / 6;
    int q = idx - n * 6;
    int beg = offs[n], end = offs[n + 1];
    const float4* f4 = (const float4*)fin;
    float4 acc = make_float4(0.f, 0.f, 0.f, 0.f);
    for (int i = beg; i < end; ++i) {
        int2 e = csr[i];
        float w = __int_as_float(e.y);
        float4 fv = f4[(size_t)e.x * 6 + q];
        acc.x += w * fv.x;
        acc.y += w * fv.y;
        acc.z += w * fv.z;
        acc.w += w * fv.w;
    }
    float inv = invh[n];
    float4 fo = f4[(size_t)n * 6 + q];
    float4 r;
    r.x = 0.5f * fo.x + inv * acc.x;
    r.y = 0.5f * fo.y + inv * acc.y;
    r.z = 0.5f * fo.z + inv * acc.z;
    r.w = 0.5f * fo.w + inv * acc.w;
    ((float4*)fout)[(size_t)n * 6 + q] = r;
}

// last diffusion step: gather + combine + transposed write to out[b][n][c]
__global__ void k_gather_out(const int* __restrict__ offs, const int2* __restrict__ csr,
                             const float* __restrict__ invh,
                             const float* __restrict__ fin, float* __restrict__ out) {
    __shared__ float ls[GON * 24];
    int t = threadIdx.x;
    int n0 = blockIdx.x * GON;
    if (t < GON * 6) {
        int ln = t / 6, q = t - 6 * ln;
        int n = n0 + ln;
        if (n < NN) {
            int beg = offs[n], end = offs[n + 1];
            const float4* f4 = (const float4*)fin;
            float4 acc = make_float4(0.f, 0.f, 0.f, 0.f);
            for (int i = beg; i < end; ++i) {
                int2 e = csr[i];
                float w = __int_as_float(e.y);
                float4 fv = f4[(size_t)e.x * 6 + q];
                acc.x += w * fv.x;
                acc.y += w * fv.y;
                acc.z += w * fv.z;
                acc.w += w * fv.w;
            }
            float inv = invh[n];
            float4 fo = f4[(size_t)n * 6 + q];
            float* d = &ls[ln * 24 + q * 4];
            d[0] = 0.5f * fo.x + inv * acc.x;
            d[1] = 0.5f * fo.y + inv * acc.y;
            d[2] = 0.5f * fo.z + inv * acc.z;
            d[3] = 0.5f * fo.w + inv * acc.w;
        }
    }
    __syncthreads();
    int cnt = NN - n0; if (cnt > GON) cnt = GON;
    int per_b = cnt * 3;
    for (int b = 0; b < BB; ++b) {
        for (int u = t; u < per_b; u += 256) {
            int n = u / 3;
            int c = u - 3 * n;
            out[(size_t)b * (NN * 3) + (size_t)n0 * 3 + u] = ls[n * 24 + b * 3 + c];
        }
    }
}

extern "C" void kernel_launch(void* const* d_in, const int* in_sizes, int n_in,
                              void* d_out, int out_size, void* d_ws, size_t ws_size,
                              hipStream_t stream) {
    const float* latent = (const float*)d_in[0];
    const float* W0 = (const float*)d_in[1];
    const float* b0 = (const float*)d_in[2];
    const float* W1 = (const float*)d_in[3];
    const float* b1 = (const float*)d_in[4];
    const float* W2 = (const float*)d_in[5];
    const float* b2 = (const float*)d_in[6];
    const float* W3 = (const float*)d_in[7];
    const float* b3 = (const float*)d_in[8];
    const float* Wx = (const float*)d_in[9];
    const float* bx = (const float*)d_in[10];
    const float* Wy = (const float*)d_in[11];
    const float* by = (const float*)d_in[12];
    const float* Wz = (const float*)d_in[13];
    const float* bz = (const float*)d_in[14];
    const float* Z  = (const float*)d_in[15];
    const float* ew = (const float*)d_in[16];
    const int*   ei = (const int*)d_in[17];
    float* out = (float*)d_out;

    float* p = (float*)d_ws;
    float* h_a     = p; p += 8192;
    float* h_b     = p; p += 8192;
    float* hp      = p; p += 16 * 8192;
    float* coef    = p; p += 7056;
    float* cpart   = p; p += CS * 7056;
    float* invh    = p; p += 100000;
    int*   cnt     = (int*)p; p += 100000;
    int*   offs    = (int*)p; p += 100016;
    int*   bsum    = (int*)p; p += 512;
    int*   bpre    = (int*)p; p += 512;
    int*   rank    = (int*)p; p += 1600000;
    int2*  csr     = (int2*)p; p += 2 * 1600000;
    float* fpart   = p; p += (size_t)FS * NN * 24;

    hipMemsetAsync(cnt, 0, NN * sizeof(int), stream);

    // MLP layer 0 + edge count (captures rank)
    K1_mlp0_count<<<32 + EBLK, 256, 0, stream>>>(latent, W0, hp, ei, cnt, rank);
    // comb0 + block sums
    K2_comb0_bsum<<<32 + NB, 256, 0, stream>>>(hp, b0, h_a, cnt, bsum);
    // block-sum scan + MLP layer 1
    K3_bscan_mlp1<<<1 + 256, 256, 0, stream>>>(bsum, bpre, offs, h_a, W1, hp);
    // comb1 + final offsets
    K4_comb1_offs<<<32 + NB, 256, 0, stream>>>(hp, h_a, b1, h_b, cnt, bpre, offs);
    // MLP layer 2 part + atomic-free CSR fill
    K5_mlp2_fill<<<256 + EBLK, 256, 0, stream>>>(h_b, W2, hp, ei, ew, offs, rank, csr);
    // comb2 + inverse degree
    K6_comb2_deg<<<32 + NB, 256, 0, stream>>>(hp, h_b, b2, h_a, offs, csr, invh);
    // MLP layer 3
    K_mlp_part3<<<256, 256, 0, stream>>>(h_a, W3, hp);
    K_mlp_comb<<<32, 256, 0, stream>>>(hp, h_a, b3, h_b);
    // coef projection
    k_coef_part<<<COB * CS, 256, 0, stream>>>(h_b, Wx, Wy, Wz, cpart);
    k_coef_comb<<<COB, 256, 0, stream>>>(cpart, bx, by, bz, coef);
    // flow partials + reg
    K11_flow_reg<<<NB * FS + 1, 256, 0, stream>>>(coef, Z, fpart, out + (size_t)BB * NN * 3);
    // flow combine
    K12_fcomb<<<(NN * 6 + 255) / 256, 256, 0, stream>>>(fpart);

    // diffusion: steps 1,2 normal; step 3 fused with transposed output
    float* f0 = fpart;
    float* f1 = fpart + (size_t)NN * 24;
    k_gather<<<(NN * 6 + 255) / 256, 256, 0, stream>>>(offs, csr, invh, f0, f1);
    k_gather<<<(NN * 6 + 255) / 256, 256, 0, stream>>>(offs, csr, invh, f1, f0);
    k_gather_out<<<(NN + GON - 1) / GON, 256, 0, stream>>>(offs, csr, invh, f0, out);
}

// Round 9
// 566.456 us; speedup vs baseline: 1.1927x; 1.0117x over previous
//
#include <hip/hip_runtime.h>
#include <math.h>

#define BB 8
#define LAT 128
#define HH 1024
#define KK 294
#define NN 100000
#define EE 1600000
#define NSTEPS 3
#define XS_HALF 64.0f

#define NB 391      // ceil(NN/256)
#define FS 4        // flow_init k-splits
#define FCH 74      // ceil(294/4)
#define FNB 196     // ceil(NN/512): flow blocks per split (2 nodes/thread)
#define CS 8        // coef j-splits (128 each)
#define COB 28      // ceil(7056/256)
#define EPT 8       // edges per thread
#define EST 200000  // EE/EPT
#define EBLK 782    // ceil(EST/256)
#define GON 40      // nodes per block in gather_out

// ---------------- device bodies ----------------

__device__ __forceinline__ void mlp_part_body(int bid, const float* __restrict__ hin,
                                              const float* __restrict__ W,
                                              float* __restrict__ part, int jdim) {
    int it = bid & 15;
    int bs = bid >> 4;
    int tx = threadIdx.x;
    int il = tx & 63;
    int jg = tx >> 6;
    int i = it * 64 + il;
    int j0 = bs * 64;

    __shared__ float hs[8 * 64];
    for (int u = tx; u < 512; u += 256) {
        int b = u >> 6, lj = u & 63;
        hs[u] = hin[b * jdim + j0 + lj];
    }
    __syncthreads();

    float acc[8];
#pragma unroll
    for (int b = 0; b < 8; ++b) acc[b] = 0.0f;
#pragma unroll
    for (int jj = 0; jj < 16; ++jj) {
        int lj = jg * 16 + jj;
        float w = W[(size_t)(j0 + lj) * HH + i];
#pragma unroll
        for (int b = 0; b < 8; ++b) acc[b] += hs[b * 64 + lj] * w;
    }

    __shared__ float red[4][8][64];
#pragma unroll
    for (int b = 0; b < 8; ++b) red[jg][b][il] = acc[b];
    __syncthreads();
    for (int u = tx; u < 512; u += 256) {
        int b = u >> 6, ii = u & 63;
        float s = red[0][b][ii] + red[1][b][ii] + red[2][b][ii] + red[3][b][ii];
        part[(size_t)bs * 8192 + b * HH + it * 64 + ii] = s;
    }
}

__device__ __forceinline__ void mlp_comb_body(int bid, const float* __restrict__ part,
                                              int nsplit, const float* __restrict__ resid,
                                              const float* __restrict__ bias,
                                              float* __restrict__ hout) {
    int idx = bid * 256 + threadIdx.x;
    if (idx >= BB * HH) return;
    int i = idx & (HH - 1);
    float s = bias[i];
    if (resid) s += resid[idx];
    for (int bs = 0; bs < nsplit; ++bs) s += part[(size_t)bs * 8192 + idx];
    hout[idx] = fmaxf(s, 0.0f);
}

// count + capture rank (one atomic per edge, batched 8/thread)
__device__ __forceinline__ void count_body(int bid, const int* __restrict__ ei,
                                           int* __restrict__ cnt, int* __restrict__ rank) {
    int gid = bid * 256 + threadIdx.x;
    if (gid >= EST) return;
    int d[EPT];
#pragma unroll
    for (int j = 0; j < EPT; ++j) d[j] = ei[EE + gid + j * EST];
#pragma unroll
    for (int j = 0; j < EPT; ++j) {
        int p = atomicAdd(&cnt[d[j]], 1);
        rank[gid + j * EST] = p;
    }
}

__device__ __forceinline__ void bsum_body(int bid, const int* __restrict__ cnt,
                                          int* __restrict__ bsum) {
    __shared__ int red[256];
    int i = bid * 256 + threadIdx.x;
    red[threadIdx.x] = (i < NN) ? cnt[i] : 0;
    __syncthreads();
    for (int off = 128; off > 0; off >>= 1) {
        if ((int)threadIdx.x < off) red[threadIdx.x] += red[threadIdx.x + off];
        __syncthreads();
    }
    if (threadIdx.x == 0) bsum[bid] = red[0];
}

__device__ __forceinline__ void bscan_body(const int* __restrict__ bsum,
                                           int* __restrict__ bpre,
                                           int* __restrict__ offs) {
    __shared__ int A[512], Bf[512];
    int t = threadIdx.x;
    A[t] = (t < NB) ? bsum[t] : 0;
    A[t + 256] = (t + 256 < NB) ? bsum[t + 256] : 0;
    __syncthreads();
    int* s = A;
    int* d = Bf;
    for (int off = 1; off < 512; off <<= 1) {
        d[t] = s[t] + ((t >= off) ? s[t - off] : 0);
        int u = t + 256;
        d[u] = s[u] + ((u >= off) ? s[u - off] : 0);
        __syncthreads();
        int* tmp = s; s = d; d = tmp;
    }
    if (t < NB) bpre[t] = (t == 0) ? 0 : s[t - 1];
    int u = t + 256;
    if (u < NB) bpre[u] = s[u - 1];
    if (t == 0) offs[NN] = s[NB - 1];
}

__device__ __forceinline__ void offs_body(int bid, const int* __restrict__ cnt,
                                          const int* __restrict__ bpre,
                                          int* __restrict__ offs) {
    __shared__ int part[256];
    int t = threadIdx.x;
    int i = bid * 256 + t;
    int v = (i < NN) ? cnt[i] : 0;
    part[t] = v;
    __syncthreads();
    for (int off = 1; off < 256; off <<= 1) {
        int u = (t >= off) ? part[t - off] : 0;
        __syncthreads();
        part[t] += u;
        __syncthreads();
    }
    if (i < NN) offs[i] = bpre[bid] + part[t] - v;
}

// atomic-free fill: p = offs[dst] + rank[e]
__device__ __forceinline__ void fill_body(int bid, const int* __restrict__ ei,
                                          const float* __restrict__ ew,
                                          const int* __restrict__ offs,
                                          const int* __restrict__ rank,
                                          int2* __restrict__ csr) {
    int gid = bid * 256 + threadIdx.x;
    if (gid >= EST) return;
    int s[EPT], d[EPT], r[EPT];
    float w[EPT];
#pragma unroll
    for (int j = 0; j < EPT; ++j) {
        int e = gid + j * EST;
        s[j] = ei[e];
        d[j] = ei[EE + e];
        w[j] = ew[e];
        r[j] = rank[e];
    }
#pragma unroll
    for (int j = 0; j < EPT; ++j) {
        int p = offs[d[j]] + r[j];
        int2 v;
        v.x = s[j];
        v.y = __float_as_int(w[j]);
        csr[p] = v;
    }
}

__device__ __forceinline__ void degcsr_body(int bid, const int* __restrict__ offs,
                                            const int2* __restrict__ csr,
                                            float* __restrict__ invh) {
    int n = bid * 256 + threadIdx.x;
    if (n >= NN) return;
    int beg = offs[n], end = offs[n + 1];
    float s = 0.0f;
    for (int i = beg; i < end; ++i) s += __int_as_float(csr[i].y);
    invh[n] = 0.5f / fmaxf(s, 1e-6f);
}

// flow_part: 2 nodes/thread, sc transposed [kk][24], float4 LDS reads
__device__ __forceinline__ void flow_part_body(int bid, const float* __restrict__ coef,
                                               const float* __restrict__ Z,
                                               float* __restrict__ fpart) {
    int s = bid / FNB;
    int blk = bid % FNB;
    int ks = s * FCH;

    __shared__ float sc[FCH * 24];
    for (int u = threadIdx.x; u < FCH * 24; u += 256) {
        int kk = u / 24, j = u - kk * 24;
        int k = ks + kk;
        sc[u] = (k < KK) ? coef[j * KK + k] : 0.0f;
    }
    __syncthreads();

    int n0 = blk * 512 + threadIdx.x * 2;
    if (n0 >= NN) return;

    float2 acc[24];
#pragma unroll
    for (int j = 0; j < 24; ++j) acc[j] = make_float2(0.f, 0.f);

    const float4* scv = (const float4*)sc;
    for (int kk = 0; kk < FCH; ++kk) {
        int k = ks + kk;
        int kz = (k < KK) ? k : (KK - 1);
        float2 z = *(const float2*)(Z + (size_t)kz * NN + n0);
        float4 c[6];
#pragma unroll
        for (int q = 0; q < 6; ++q) c[q] = scv[kk * 6 + q];
        const float* cf = (const float*)c;
#pragma unroll
        for (int j = 0; j < 24; ++j) {
            acc[j].x += cf[j] * z.x;
            acc[j].y += cf[j] * z.y;
        }
    }

    // reorder j=(t*8+b) -> output position b*3+t, two nodes contiguous
    float buf[48];
#pragma unroll
    for (int j = 0; j < 24; ++j) {
        int b = j & 7, t = j >> 3;
        buf[b * 3 + t] = acc[j].x;
        buf[24 + b * 3 + t] = acc[j].y;
    }
    float4* fr = (float4*)(fpart + (size_t)s * (NN * 24) + (size_t)n0 * 24);
#pragma unroll
    for (int q = 0; q < 12; ++q) fr[q] = ((const float4*)buf)[q];
}

__device__ __forceinline__ void flow_comb_body(int bid, float* __restrict__ fpart) {
    int idx = bid * 256 + threadIdx.x;
    if (idx >= NN * 6) return;
    float4* p0 = (float4*)fpart;
    const float4* p1 = p0 + NN * 6;
    const float4* p2 = p1 + NN * 6;
    const float4* p3 = p2 + NN * 6;
    float4 a = p0[idx], b = p1[idx], c = p2[idx], d = p3[idx];
    float4 r;
    r.x = XS_HALF * (a.x + b.x + c.x + d.x);
    r.y = XS_HALF * (a.y + b.y + c.y + d.y);
    r.z = XS_HALF * (a.z + b.z + c.z + d.z);
    r.w = XS_HALF * (a.w + b.w + c.w + d.w);
    p0[idx] = r;
}

__device__ __forceinline__ void reg_body(const float* __restrict__ coef,
                                         float* __restrict__ out_reg) {
    __shared__ float red[256];
    float s = 0.0f;
    for (int i = threadIdx.x; i < 3 * BB * KK; i += 256) {
        float v = coef[i];
        s += v * v;
    }
    red[threadIdx.x] = s;
    __syncthreads();
    for (int off = 128; off > 0; off >>= 1) {
        if ((int)threadIdx.x < off) red[threadIdx.x] += red[threadIdx.x + off];
        __syncthreads();
    }
    if (threadIdx.x == 0) out_reg[0] = 1e-4f * sqrtf(red[0]);
}

// ---------------- fused kernels ----------------

__global__ void K1_mlp0_count(const float* __restrict__ latent, const float* __restrict__ W0,
                              float* __restrict__ part, const int* __restrict__ ei,
                              int* __restrict__ cnt, int* __restrict__ rank) {
    if (blockIdx.x < 32) mlp_part_body(blockIdx.x, latent, W0, part, LAT);
    else count_body(blockIdx.x - 32, ei, cnt, rank);
}

__global__ void K2_comb0_bsum(const float* __restrict__ part, const float* __restrict__ b0,
                              float* __restrict__ hout, const int* __restrict__ cnt,
                              int* __restrict__ bsum) {
    if (blockIdx.x < 32) mlp_comb_body(blockIdx.x, part, 2, nullptr, b0, hout);
    else bsum_body(blockIdx.x - 32, cnt, bsum);
}

__global__ void K3_bscan_mlp1(const int* __restrict__ bsum, int* __restrict__ bpre,
                              int* __restrict__ offs, const float* __restrict__ hin,
                              const float* __restrict__ W1, float* __restrict__ part) {
    if (blockIdx.x == 0) bscan_body(bsum, bpre, offs);
    else mlp_part_body(blockIdx.x - 1, hin, W1, part, HH);
}

__global__ void K4_comb1_offs(const float* __restrict__ part, const float* __restrict__ resid,
                              const float* __restrict__ b1, float* __restrict__ hout,
                              const int* __restrict__ cnt, const int* __restrict__ bpre,
                              int* __restrict__ offs) {
    if (blockIdx.x < 32) mlp_comb_body(blockIdx.x, part, 16, resid, b1, hout);
    else offs_body(blockIdx.x - 32, cnt, bpre, offs);
}

// MLP layer 2 part + CSR fill (both independent)
__global__ void K5_mlp2_fill(const float* __restrict__ hin, const float* __restrict__ W2,
                             float* __restrict__ part, const int* __restrict__ ei,
                             const float* __restrict__ ew, const int* __restrict__ offs,
                             const int* __restrict__ rank, int2* __restrict__ csr) {
    if (blockIdx.x < 256) mlp_part_body(blockIdx.x, hin, W2, part, HH);
    else fill_body(blockIdx.x - 256, ei, ew, offs, rank, csr);
}

__global__ void K6_comb2_deg(const float* __restrict__ part, const float* __restrict__ resid,
                             const float* __restrict__ bias, float* __restrict__ hout,
                             const int* __restrict__ offs, const int2* __restrict__ csr,
                             float* __restrict__ invh) {
    if (blockIdx.x < 32) mlp_comb_body(blockIdx.x, part, 16, resid, bias, hout);
    else degcsr_body(blockIdx.x - 32, offs, csr, invh);
}

__global__ void K_mlp_part3(const float* __restrict__ hin, const float* __restrict__ W,
                            float* __restrict__ part) {
    mlp_part_body(blockIdx.x, hin, W, part, HH);
}

__global__ void K_mlp_comb(const float* __restrict__ part, const float* __restrict__ resid,
                           const float* __restrict__ bias, float* __restrict__ hout) {
    mlp_comb_body(blockIdx.x, part, 16, resid, bias, hout);
}

__global__ void k_coef_part(const float* __restrict__ h,
                            const float* __restrict__ Wx,
                            const float* __restrict__ Wy,
                            const float* __restrict__ Wz,
                            float* __restrict__ cpart) {
    int s = blockIdx.x / COB;
    int blk = blockIdx.x % COB;
    int o = blk * 256 + threadIdx.x;
    if (o >= 3 * BB * KK) return;
    int t = o / (BB * KK);
    int r = o % (BB * KK);
    int b = r / KK, k = r % KK;
    const float* W = (t == 0) ? Wx : ((t == 1) ? Wy : Wz);
    const float* hr = h + b * HH;
    int j0 = s * 128;
    float acc = 0.0f;
#pragma unroll 8
    for (int j = 0; j < 128; ++j) acc += hr[j0 + j] * W[(size_t)(j0 + j) * KK + k];
    cpart[(size_t)s * 7056 + o] = acc;
}

__global__ void k_coef_comb(const float* __restrict__ cpart,
                            const float* __restrict__ bx,
                            const float* __restrict__ by,
                            const float* __restrict__ bz,
                            float* __restrict__ coef) {
    int o = blockIdx.x * 256 + threadIdx.x;
    if (o >= 3 * BB * KK) return;
    int t = o / (BB * KK);
    int k = o % KK;
    float s = ((t == 0) ? bx : ((t == 1) ? by : bz))[k];
#pragma unroll
    for (int i = 0; i < CS; ++i) s += cpart[(size_t)i * 7056 + o];
    coef[o] = s;
}

// flow partials + reg
__global__ void K11_flow_reg(const float* __restrict__ coef, const float* __restrict__ Z,
                             float* __restrict__ fpart, float* __restrict__ out_reg) {
    if (blockIdx.x < FS * FNB) flow_part_body(blockIdx.x, coef, Z, fpart);
    else reg_body(coef, out_reg);
}

__global__ void K12_fcomb(float* __restrict__ fpart) {
    flow_comb_body(blockIdx.x, fpart);
}

// ---------------- diffusion ----------------
__global__ void k_gather(const int* __restrict__ offs, const int2* __restrict__ csr,
                         const float* __restrict__ invh,
                         const float* __restrict__ fin, float* __restrict__ fout) {
    int idx = blockIdx.x * 256 + threadIdx.x;   // NN*6
    if (idx >= NN * 6) return;
    int n = idx / 6;
    int q = idx - n * 6;
    int beg = offs[n], end = offs[n + 1];
    const float4* f4 = (const float4*)fin;
    float4 acc = make_float4(0.f, 0.f, 0.f, 0.f);
    for (int i = beg; i < end; ++i) {
        int2 e = csr[i];
        float w = __int_as_float(e.y);
        float4 fv = f4[(size_t)e.x * 6 + q];
        acc.x += w * fv.x;
        acc.y += w * fv.y;
        acc.z += w * fv.z;
        acc.w += w * fv.w;
    }
    float inv = invh[n];
    float4 fo = f4[(size_t)n * 6 + q];
    float4 r;
    r.x = 0.5f * fo.x + inv * acc.x;
    r.y = 0.5f * fo.y + inv * acc.y;
    r.z = 0.5f * fo.z + inv * acc.z;
    r.w = 0.5f * fo.w + inv * acc.w;
    ((float4*)fout)[(size_t)n * 6 + q] = r;
}

// last diffusion step: gather + combine + transposed write to out[b][n][c]
__global__ void k_gather_out(const int* __restrict__ offs, const int2* __restrict__ csr,
                             const float* __restrict__ invh,
                             const float* __restrict__ fin, float* __restrict__ out) {
    __shared__ float ls[GON * 24];
    int t = threadIdx.x;
    int n0 = blockIdx.x * GON;
    if (t < GON * 6) {
        int ln = t / 6, q = t - 6 * ln;
        int n = n0 + ln;
        if (n < NN) {
            int beg = offs[n], end = offs[n + 1];
            const float4* f4 = (const float4*)fin;
            float4 acc = make_float4(0.f, 0.f, 0.f, 0.f);
            for (int i = beg; i < end; ++i) {
                int2 e = csr[i];
                float w = __int_as_float(e.y);
                float4 fv = f4[(size_t)e.x * 6 + q];
                acc.x += w * fv.x;
                acc.y += w * fv.y;
                acc.z += w * fv.z;
                acc.w += w * fv.w;
            }
            float inv = invh[n];
            float4 fo = f4[(size_t)n * 6 + q];
            float* d = &ls[ln * 24 + q * 4];
            d[0] = 0.5f * fo.x + inv * acc.x;
            d[1] = 0.5f * fo.y + inv * acc.y;
            d[2] = 0.5f * fo.z + inv * acc.z;
            d[3] = 0.5f * fo.w + inv * acc.w;
        }
    }
    __syncthreads();
    int cnt = NN - n0; if (cnt > GON) cnt = GON;
    int per_b = cnt * 3;
    for (int b = 0; b < BB; ++b) {
        for (int u = t; u < per_b; u += 256) {
            int n = u / 3;
            int c = u - 3 * n;
            out[(size_t)b * (NN * 3) + (size_t)n0 * 3 + u] = ls[n * 24 + b * 3 + c];
        }
    }
}

extern "C" void kernel_launch(void* const* d_in, const int* in_sizes, int n_in,
                              void* d_out, int out_size, void* d_ws, size_t ws_size,
                              hipStream_t stream) {
    const float* latent = (const float*)d_in[0];
    const float* W0 = (const float*)d_in[1];
    const float* b0 = (const float*)d_in[2];
    const float* W1 = (const float*)d_in[3];
    const float* b1 = (const float*)d_in[4];
    const float* W2 = (const float*)d_in[5];
    const float* b2 = (const float*)d_in[6];
    const float* W3 = (const float*)d_in[7];
    const float* b3 = (const float*)d_in[8];
    const float* Wx = (const float*)d_in[9];
    const float* bx = (const float*)d_in[10];
    const float* Wy = (const float*)d_in[11];
    const float* by = (const float*)d_in[12];
    const float* Wz = (const float*)d_in[13];
    const float* bz = (const float*)d_in[14];
    const float* Z  = (const float*)d_in[15];
    const float* ew = (const float*)d_in[16];
    const int*   ei = (const int*)d_in[17];
    float* out = (float*)d_out;

    float* p = (float*)d_ws;
    float* h_a     = p; p += 8192;
    float* h_b     = p; p += 8192;
    float* hp      = p; p += 16 * 8192;
    float* coef    = p; p += 7056;
    float* cpart   = p; p += CS * 7056;
    float* invh    = p; p += 100000;
    int*   cnt     = (int*)p; p += 100000;
    int*   offs    = (int*)p; p += 100016;
    int*   bsum    = (int*)p; p += 512;
    int*   bpre    = (int*)p; p += 512;
    int*   rank    = (int*)p; p += 1600000;
    int2*  csr     = (int2*)p; p += 2 * 1600000;
    float* fpart   = p; p += (size_t)FS * NN * 24;

    hipMemsetAsync(cnt, 0, NN * sizeof(int), stream);

    // MLP layer 0 + edge count (captures rank)
    K1_mlp0_count<<<32 + EBLK, 256, 0, stream>>>(latent, W0, hp, ei, cnt, rank);
    // comb0 + block sums
    K2_comb0_bsum<<<32 + NB, 256, 0, stream>>>(hp, b0, h_a, cnt, bsum);
    // block-sum scan + MLP layer 1
    K3_bscan_mlp1<<<1 + 256, 256, 0, stream>>>(bsum, bpre, offs, h_a, W1, hp);
    // comb1 + final offsets
    K4_comb1_offs<<<32 + NB, 256, 0, stream>>>(hp, h_a, b1, h_b, cnt, bpre, offs);
    // MLP layer 2 part + atomic-free CSR fill
    K5_mlp2_fill<<<256 + EBLK, 256, 0, stream>>>(h_b, W2, hp, ei, ew, offs, rank, csr);
    // comb2 + inverse degree
    K6_comb2_deg<<<32 + NB, 256, 0, stream>>>(hp, h_b, b2, h_a, offs, csr, invh);
    // MLP layer 3
    K_mlp_part3<<<256, 256, 0, stream>>>(h_a, W3, hp);
    K_mlp_comb<<<32, 256, 0, stream>>>(hp, h_a, b3, h_b);
    // coef projection
    k_coef_part<<<COB * CS, 256, 0, stream>>>(h_b, Wx, Wy, Wz, cpart);
    k_coef_comb<<<COB, 256, 0, stream>>>(cpart, bx, by, bz, coef);
    // flow partials + reg
    K11_flow_reg<<<FS * FNB + 1, 256, 0, stream>>>(coef, Z, fpart, out + (size_t)BB * NN * 3);
    // flow combine
    K12_fcomb<<<(NN * 6 + 255) / 256, 256, 0, stream>>>(fpart);

    // diffusion: steps 1,2 normal; step 3 fused with transposed output
    float* f0 = fpart;
    float* f1 = fpart + (size_t)NN * 24;
    k_gather<<<(NN * 6 + 255) / 256, 256, 0, stream>>>(offs, csr, invh, f0, f1);
    k_gather<<<(NN * 6 + 255) / 256, 256, 0, stream>>>(offs, csr, invh, f1, f0);
    k_gather_out<<<(NN + GON - 1) / GON, 256, 0, stream>>>(offs, csr, invh, f0, out);
}